// Round 1
// baseline (98.437 us; speedup 1.0000x reference)
//
#include <hip/hip_runtime.h>
#include <stdint.h>

#define F 1024
#define H 256
#define E 64
#define D 64
#define B 4096
#define NN 1280  // N = F + H

// ---------------- K0: probe mask dtype (byte / int32 / float32) ----------------
// Diagonal entries mask[i][i] are guaranteed True (==1). Check i = 0..255 under
// all three interpretations; all reads stay within the smallest possible buffer
// (F*NN bytes): max byte offset 4*(255*1281)+3 = 1,306,623 < 1,310,720.
__global__ void probe_mask_kernel(const void* __restrict__ mask, int* __restrict__ flag) {
    __shared__ int s_byte, s_int, s_float;
    int t = threadIdx.x;
    if (t == 0) { s_byte = 1; s_int = 1; s_float = 1; }
    __syncthreads();
    long idx = (long)t * NN + t;
    const uint8_t* mb = (const uint8_t*)mask;
    const int*     mi = (const int*)mask;
    const float*   mf = (const float*)mask;
    if (mb[idx] != 1)    atomicAnd(&s_byte, 0);
    if (mi[idx] != 1)    atomicAnd(&s_int, 0);
    if (mf[idx] != 1.0f) atomicAnd(&s_float, 0);
    __syncthreads();
    if (t == 0) {
        int mode = 0;
        if (s_byte) mode = 0;
        else if (s_int) mode = 1;
        else if (s_float) mode = 2;
        flag[0] = mode;
    }
}

// ---------------- K1: feat_proj (F x D) and full_proj (NN x D) ----------------
// fp[f][d] = sum_e feat_emb[f][e] * w_kernel[e][d]
// gp[n][d] = sum_e full[n][e]     * w_kernel[E+e][d]
__global__ void proj_kernel(const float* __restrict__ feat_emb,
                            const float* __restrict__ hidden_emb,
                            const float* __restrict__ w_kernel,
                            float* __restrict__ fp, float* __restrict__ gp) {
    int tid = threadIdx.x;
    int r = blockIdx.x * 4 + (tid >> 6);
    int d = tid & 63;
    const float* emb;
    const float* W;
    float* outp;
    if (r < F) {
        emb = feat_emb + (size_t)r * E;
        W = w_kernel;                      // Wa
        outp = fp + (size_t)r * D + d;
    } else {
        int rn = r - F;
        emb = (rn < F) ? (feat_emb + (size_t)rn * E)
                       : (hidden_emb + (size_t)(rn - F) * E);
        W = w_kernel + (size_t)E * D;      // Wb
        outp = gp + (size_t)rn * D + d;
    }
    float acc = 0.f;
#pragma unroll
    for (int e = 0; e < E; ++e) acc = fmaf(emb[e], W[e * D + d], acc);
    *outp = acc;
}

// ---------------- K2: masked score -> softmax -> context ----------------
// One wave per row f. Only compute score where mask is true (~26 of 1280).
__global__ void attn_ctx_kernel(const float* __restrict__ feat_emb,
                                const float* __restrict__ hidden_emb,
                                const void*  __restrict__ mask,
                                const float* __restrict__ w_bias,
                                const float* __restrict__ u_kernel,
                                const float* __restrict__ fp,
                                const float* __restrict__ gp,
                                const int*   __restrict__ flag,
                                float* __restrict__ ctx) {
    int tid = threadIdx.x;
    int f = blockIdx.x * 4 + (tid >> 6);
    int lane = tid & 63;
    int mode = flag[0];
    float uk  = u_kernel[lane];
    float bv  = w_bias[lane];
    float fpv = fp[(size_t)f * D + lane];
    float denom = 0.f, cacc = 0.f;
    const uint8_t* mb = (const uint8_t*)mask;
    const int*     mi = (const int*)mask;
    const float*   mf = (const float*)mask;
    for (int nb = 0; nb < NN; nb += 64) {
        long midx = (long)f * NN + nb + lane;
        bool mv;
        if (mode == 0)      mv = (mb[midx] != 0);
        else if (mode == 1) mv = (mi[midx] != 0);
        else                mv = (mf[midx] != 0.f);
        unsigned long long bal = __ballot(mv);
        while (bal) {
            int bit = __ffsll((unsigned long long)bal) - 1;
            bal &= bal - 1;
            int n = nb + bit;
            float gpv = gp[(size_t)n * D + lane];
            float t = uk * tanhf(fpv + gpv + bv);
#pragma unroll
            for (int off = 32; off; off >>= 1) t += __shfl_xor(t, off);
            float es = expf(t);          // uniform across lanes
            denom += es;
            float fullv = (n < F) ? feat_emb[(size_t)n * E + lane]
                                  : hidden_emb[(size_t)(n - F) * E + lane];
            cacc = fmaf(es, fullv, cacc);
        }
    }
    ctx[(size_t)f * D + lane] = cacc / denom;
}

// ---------------- K3: out = values @ ctx  (4096x1024)·(1024x64) ----------------
// Block = 256 threads = 4 waves. Wave pair (pair,half): 8 rows, K split in two
// halves; LDS combine. 256 blocks -> 1024 waves (1 wave/SIMD).
__global__ void out_kernel(const float* __restrict__ values,
                           const float* __restrict__ ctx,
                           float* __restrict__ out) {
    __shared__ float red[2][8][64];
    int tid  = threadIdx.x;
    int wid  = tid >> 6;
    int lane = tid & 63;
    int pair = wid >> 1;   // row group within block
    int half = wid & 1;    // k half
    int b0 = (blockIdx.x * 2 + pair) * 8;
    int k0 = half * (F / 2);
    float acc[8] = {0.f, 0.f, 0.f, 0.f, 0.f, 0.f, 0.f, 0.f};
    for (int k = k0; k < k0 + F / 2; k += 4) {
        float c0 = ctx[(size_t)(k + 0) * D + lane];
        float c1 = ctx[(size_t)(k + 1) * D + lane];
        float c2 = ctx[(size_t)(k + 2) * D + lane];
        float c3 = ctx[(size_t)(k + 3) * D + lane];
#pragma unroll
        for (int r = 0; r < 8; ++r) {
            const float4 v = *reinterpret_cast<const float4*>(
                values + (size_t)(b0 + r) * F + k);
            float a = acc[r];
            a = fmaf(v.x, c0, a);
            a = fmaf(v.y, c1, a);
            a = fmaf(v.z, c2, a);
            a = fmaf(v.w, c3, a);
            acc[r] = a;
        }
    }
    if (half == 1) {
#pragma unroll
        for (int r = 0; r < 8; ++r) red[pair][r][lane] = acc[r];
    }
    __syncthreads();
    if (half == 0) {
#pragma unroll
        for (int r = 0; r < 8; ++r)
            out[(size_t)(b0 + r) * D + lane] = acc[r] + red[pair][r][lane];
    }
}

extern "C" void kernel_launch(void* const* d_in, const int* in_sizes, int n_in,
                              void* d_out, int out_size, void* d_ws, size_t ws_size,
                              hipStream_t stream) {
    const float* values     = (const float*)d_in[0];
    const float* feat_emb   = (const float*)d_in[1];
    const float* hidden_emb = (const float*)d_in[2];
    const float* w_kernel   = (const float*)d_in[3];
    const float* w_bias     = (const float*)d_in[4];
    const float* u_kernel   = (const float*)d_in[5];
    const void*  mask       = (const void*)d_in[6];
    float* out = (float*)d_out;

    int*   flag = (int*)d_ws;
    float* wsf  = (float*)d_ws;
    float* fp   = wsf + 64;            // F*D floats
    float* gp   = fp + F * D;          // NN*D floats
    float* ctx  = gp + NN * D;         // F*E floats

    probe_mask_kernel<<<1, 256, 0, stream>>>(mask, flag);
    proj_kernel<<<(F + NN) / 4, 256, 0, stream>>>(feat_emb, hidden_emb, w_kernel, fp, gp);
    attn_ctx_kernel<<<F / 4, 256, 0, stream>>>(feat_emb, hidden_emb, mask, w_bias,
                                               u_kernel, fp, gp, flag, ctx);
    out_kernel<<<B / 16, 256, 0, stream>>>(values, ctx, out);
}

// Round 3
// 72.595 us; speedup vs baseline: 1.3560x; 1.3560x over previous
//
#include <hip/hip_runtime.h>
#include <stdint.h>

#define F 1024
#define H 256
#define E 64
#define D 64
#define B 4096
#define NN 1280  // N = F + H

// ---------------- probe logic (runs as extra block of proj kernel) ----------
// Diagonal entries mask[i][i] are guaranteed True (==1). Check i = 0..255 under
// byte/int32/float interpretations; all reads stay within the smallest possible
// buffer (F*NN bytes).
__device__ void probe_mask_body(const void* __restrict__ mask, int* __restrict__ flag) {
    __shared__ int s_byte, s_int, s_float;
    int t = threadIdx.x;
    if (t == 0) { s_byte = 1; s_int = 1; s_float = 1; }
    __syncthreads();
    long idx = (long)t * NN + t;
    const uint8_t* mb = (const uint8_t*)mask;
    const int*     mi = (const int*)mask;
    const float*   mf = (const float*)mask;
    if (mb[idx] != 1)    atomicAnd(&s_byte, 0);
    if (mi[idx] != 1)    atomicAnd(&s_int, 0);
    if (mf[idx] != 1.0f) atomicAnd(&s_float, 0);
    __syncthreads();
    if (t == 0) {
        int mode = 0;
        if (s_byte) mode = 0;
        else if (s_int) mode = 1;
        else if (s_float) mode = 2;
        flag[0] = mode;
    }
}

// ---------------- K1: feat_proj (F x D), full_proj (NN x D), + probe --------
__global__ void proj_kernel(const float* __restrict__ feat_emb,
                            const float* __restrict__ hidden_emb,
                            const float* __restrict__ w_kernel,
                            const void*  __restrict__ mask,
                            float* __restrict__ fp, float* __restrict__ gp,
                            int* __restrict__ flag) {
    if (blockIdx.x == (F + NN) / 4) {  // last block: mask dtype probe
        probe_mask_body(mask, flag);
        return;
    }
    int tid = threadIdx.x;
    int r = blockIdx.x * 4 + (tid >> 6);
    int d = tid & 63;
    const float* emb;
    const float* W;
    float* outp;
    if (r < F) {
        emb = feat_emb + (size_t)r * E;
        W = w_kernel;                      // Wa
        outp = fp + (size_t)r * D + d;
    } else {
        int rn = r - F;
        emb = (rn < F) ? (feat_emb + (size_t)rn * E)
                       : (hidden_emb + (size_t)(rn - F) * E);
        W = w_kernel + (size_t)E * D;      // Wb
        outp = gp + (size_t)rn * D + d;
    }
    float acc = 0.f;
#pragma unroll
    for (int e = 0; e < E; ++e) acc = fmaf(emb[e], W[e * D + d], acc);
    *outp = acc;
}

// ---------------- K2: masked score -> softmax -> context ----------------
// One wave per row f. Only compute score where mask is true (~26 of 1280).
__global__ void attn_ctx_kernel(const float* __restrict__ feat_emb,
                                const float* __restrict__ hidden_emb,
                                const void*  __restrict__ mask,
                                const float* __restrict__ w_bias,
                                const float* __restrict__ u_kernel,
                                const float* __restrict__ fp,
                                const float* __restrict__ gp,
                                const int*   __restrict__ flag,
                                float* __restrict__ ctx) {
    int tid = threadIdx.x;
    int f = blockIdx.x * 4 + (tid >> 6);
    int lane = tid & 63;
    int mode = flag[0];
    float uk  = u_kernel[lane];
    float bv  = w_bias[lane];
    float fpv = fp[(size_t)f * D + lane];
    float denom = 0.f, cacc = 0.f;
    const uint8_t* mb = (const uint8_t*)mask;
    const int*     mi = (const int*)mask;
    const float*   mf = (const float*)mask;
    for (int nb = 0; nb < NN; nb += 64) {
        long midx = (long)f * NN + nb + lane;
        bool mv;
        if (mode == 0)      mv = (mb[midx] != 0);
        else if (mode == 1) mv = (mi[midx] != 0);
        else                mv = (mf[midx] != 0.f);
        unsigned long long bal = __ballot(mv);
        while (bal) {
            int bit = __ffsll((unsigned long long)bal) - 1;
            bal &= bal - 1;
            int n = nb + bit;
            float gpv = gp[(size_t)n * D + lane];
            float t = uk * tanhf(fpv + gpv + bv);
#pragma unroll
            for (int off = 32; off; off >>= 1) t += __shfl_xor(t, off);
            float es = expf(t);          // uniform across lanes
            denom += es;
            float fullv = (n < F) ? feat_emb[(size_t)n * E + lane]
                                  : hidden_emb[(size_t)(n - F) * E + lane];
            cacc = fmaf(es, fullv, cacc);
        }
    }
    ctx[(size_t)f * D + lane] = cacc / denom;
}

// ---------------- K3: out = values @ ctx  (4096x1024)·(1024x64) ----------------
// 512 blocks x 512 threads (8 waves). Block computes 8 output rows; wave w
// accumulates k-slice [w*128, w*128+128); LDS tree-combine. 4096 waves total
// (16/CU, 4/SIMD) to hide load latency.
#define OK_ROWS 8
#define OK_WAVES 8
__global__ __launch_bounds__(512, 2)
void out_kernel(const float* __restrict__ values,
                const float* __restrict__ ctx,
                float* __restrict__ out) {
    __shared__ float red[OK_WAVES][OK_ROWS][64];  // 16 KB
    int tid  = threadIdx.x;
    int wid  = tid >> 6;
    int lane = tid & 63;
    int b0 = blockIdx.x * OK_ROWS;
    int k0 = wid * (F / OK_WAVES);
    float acc[OK_ROWS] = {0.f, 0.f, 0.f, 0.f, 0.f, 0.f, 0.f, 0.f};
    for (int k = k0; k < k0 + F / OK_WAVES; k += 4) {
        float c0 = ctx[(size_t)(k + 0) * D + lane];
        float c1 = ctx[(size_t)(k + 1) * D + lane];
        float c2 = ctx[(size_t)(k + 2) * D + lane];
        float c3 = ctx[(size_t)(k + 3) * D + lane];
#pragma unroll
        for (int r = 0; r < OK_ROWS; ++r) {
            const float4 v = *reinterpret_cast<const float4*>(
                values + (size_t)(b0 + r) * F + k);
            float a = acc[r];
            a = fmaf(v.x, c0, a);
            a = fmaf(v.y, c1, a);
            a = fmaf(v.z, c2, a);
            a = fmaf(v.w, c3, a);
            acc[r] = a;
        }
    }
#pragma unroll
    for (int r = 0; r < OK_ROWS; ++r) red[wid][r][lane] = acc[r];
    __syncthreads();
    // wave wid reduces row wid across the 8 wave-partials
    float s = 0.f;
#pragma unroll
    for (int w = 0; w < OK_WAVES; ++w) s += red[w][wid][lane];
    out[(size_t)(b0 + wid) * D + lane] = s;
}

extern "C" void kernel_launch(void* const* d_in, const int* in_sizes, int n_in,
                              void* d_out, int out_size, void* d_ws, size_t ws_size,
                              hipStream_t stream) {
    const float* values     = (const float*)d_in[0];
    const float* feat_emb   = (const float*)d_in[1];
    const float* hidden_emb = (const float*)d_in[2];
    const float* w_kernel   = (const float*)d_in[3];
    const float* w_bias     = (const float*)d_in[4];
    const float* u_kernel   = (const float*)d_in[5];
    const void*  mask       = (const void*)d_in[6];
    float* out = (float*)d_out;

    int*   flag = (int*)d_ws;
    float* wsf  = (float*)d_ws;
    float* fp   = wsf + 64;            // F*D floats
    float* gp   = fp + F * D;          // NN*D floats
    float* ctx  = gp + NN * D;         // F*E floats

    proj_kernel<<<(F + NN) / 4 + 1, 256, 0, stream>>>(feat_emb, hidden_emb, w_kernel,
                                                      mask, fp, gp, flag);
    attn_ctx_kernel<<<F / 4, 256, 0, stream>>>(feat_emb, hidden_emb, mask, w_bias,
                                               u_kernel, fp, gp, flag, ctx);
    out_kernel<<<B / OK_ROWS, 512, 0, stream>>>(values, ctx, out);
}

// Round 6
// 28.406 us; speedup vs baseline: 3.4653x; 2.5556x over previous
//
#include <hip/hip_runtime.h>
#include <stdint.h>

#define F 1024
#define H 256
#define E 64
#define D 64
#define B 4096
#define NN 1280  // N = F + H

typedef __attribute__((ext_vector_type(8))) short bf16x8;
typedef __attribute__((ext_vector_type(4))) float f32x4;

__device__ inline uint16_t f2bf_rne(float x) {
    union { float f; uint32_t u; } v; v.f = x;
    uint32_t u = v.u + 0x7fffu + ((v.u >> 16) & 1u);
    return (uint16_t)(u >> 16);
}
__device__ inline float bf2f(uint16_t h) {
    union { uint32_t u; float f; } v; v.u = ((uint32_t)h) << 16;
    return v.f;
}

// ---------------- probe (extra block of proj kernel) ----------
__device__ void probe_mask_body(const void* __restrict__ mask, int* __restrict__ flag) {
    __shared__ int s_byte, s_int, s_float;
    int t = threadIdx.x;
    if (t == 0) { s_byte = 1; s_int = 1; s_float = 1; }
    __syncthreads();
    long idx = (long)t * NN + t;
    const uint8_t* mb = (const uint8_t*)mask;
    const int*     mi = (const int*)mask;
    const float*   mf = (const float*)mask;
    if (mb[idx] != 1)    atomicAnd(&s_byte, 0);
    if (mi[idx] != 1)    atomicAnd(&s_int, 0);
    if (mf[idx] != 1.0f) atomicAnd(&s_float, 0);
    __syncthreads();
    if (t == 0) {
        int mode = 0;
        if (s_byte) mode = 0;
        else if (s_int) mode = 1;
        else if (s_float) mode = 2;
        flag[0] = mode;
    }
}

// ---------------- K1: feat_proj (F x D), full_proj (NN x D), + probe --------
__global__ void proj_kernel(const float* __restrict__ feat_emb,
                            const float* __restrict__ hidden_emb,
                            const float* __restrict__ w_kernel,
                            const void*  __restrict__ mask,
                            float* __restrict__ fp, float* __restrict__ gp,
                            int* __restrict__ flag) {
    if (blockIdx.x == (F + NN) / 4) {  // last block: mask dtype probe
        probe_mask_body(mask, flag);
        return;
    }
    int tid = threadIdx.x;
    int r = blockIdx.x * 4 + (tid >> 6);
    int d = tid & 63;
    const float* emb;
    const float* W;
    float* outp;
    if (r < F) {
        emb = feat_emb + (size_t)r * E;
        W = w_kernel;                      // Wa
        outp = fp + (size_t)r * D + d;
    } else {
        int rn = r - F;
        emb = (rn < F) ? (feat_emb + (size_t)rn * E)
                       : (hidden_emb + (size_t)(rn - F) * E);
        W = w_kernel + (size_t)E * D;      // Wb
        outp = gp + (size_t)rn * D + d;
    }
    float acc = 0.f;
#pragma unroll
    for (int e = 0; e < E; ++e) acc = fmaf(emb[e], W[e * D + d], acc);
    *outp = acc;
}

// ---------------- K2: masked score -> softmax -> context (packed bf16 hi/lo) --
// 1 block per row f; 4 waves split the n-range (320 each); LDS combine;
// wave 0 finalizes and writes ctx directly in MFMA B-fragment order:
//   ctxB[((ks*4 + nt)*64 + l)*8 + j] = ctx[k][n],
//   k = ks*32 + (l>>4)*8 + j (k == f), n = nt*16 + (l&15).
__global__ __launch_bounds__(256)
void attn_ctx_kernel(const float* __restrict__ feat_emb,
                     const float* __restrict__ hidden_emb,
                     const void*  __restrict__ mask,
                     const float* __restrict__ w_bias,
                     const float* __restrict__ u_kernel,
                     const float* __restrict__ fp,
                     const float* __restrict__ gp,
                     const int*   __restrict__ flag,
                     uint16_t* __restrict__ ctxB_hi,
                     uint16_t* __restrict__ ctxB_lo) {
    __shared__ float s_cacc[4][64];
    __shared__ float s_den[4];
    int tid = threadIdx.x;
    int w = tid >> 6, lane = tid & 63;
    int f = blockIdx.x;
    int mode = flag[0];
    float uk  = u_kernel[lane];
    float bv  = w_bias[lane];
    float fpv = fp[(size_t)f * D + lane];
    float denom = 0.f, cacc = 0.f;
    const uint8_t* mb = (const uint8_t*)mask;
    const int*     mi = (const int*)mask;
    const float*   mf = (const float*)mask;
    for (int nb = w * 320; nb < w * 320 + 320; nb += 64) {
        long midx = (long)f * NN + nb + lane;
        bool mv;
        if (mode == 0)      mv = (mb[midx] != 0);
        else if (mode == 1) mv = (mi[midx] != 0);
        else                mv = (mf[midx] != 0.f);
        unsigned long long bal = __ballot(mv);
        while (bal) {
            int bit = __ffsll(bal) - 1;
            bal &= bal - 1;
            int n = nb + bit;
            float gpv = gp[(size_t)n * D + lane];
            float t = uk * tanhf(fpv + gpv + bv);
#pragma unroll
            for (int off = 32; off; off >>= 1) t += __shfl_xor(t, off);
            float es = expf(t);          // uniform across lanes
            denom += es;
            float fullv = (n < F) ? feat_emb[(size_t)n * E + lane]
                                  : hidden_emb[(size_t)(n - F) * E + lane];
            cacc = fmaf(es, fullv, cacc);
        }
    }
    s_cacc[w][lane] = cacc;
    if (lane == 0) s_den[w] = denom;
    __syncthreads();
    if (w == 0) {
        float c = s_cacc[0][lane] + s_cacc[1][lane] + s_cacc[2][lane] + s_cacc[3][lane];
        float dn = s_den[0] + s_den[1] + s_den[2] + s_den[3];
        c /= dn;
        uint16_t hi = f2bf_rne(c);
        float lof = c - bf2f(hi);
        uint16_t lo = f2bf_rne(lof);
        int ks = f >> 5, kk = f & 31;
        int ch = kk >> 3, j = kk & 7;
        int l  = ch * 16 + (lane & 15);
        int nt = lane >> 4;
        int off = ((ks * 4 + nt) * 64 + l) * 8 + j;
        ctxB_hi[off] = hi;
        ctxB_lo[off] = lo;
    }
}

// ---------------- K3: out = values @ ctx via split-bf16 MFMA -----------------
// Grid 256 blocks x 1024 thr (16 waves). Block owns 16 output rows (one MFMA
// m-tile), full N=64 (4 n-tiles). Wave w covers k in [w*64, w*64+64) = 2
// k-steps of 32. A-fragments loaded straight from fp32 values (2 float4/lane,
// 128B-chunk coalesced) and split to bf16 hi/lo in-register. B-fragments are
// pre-packed contiguous 16B/lane. hi*hi + hi*lo + lo*hi. LDS reduce 16 partials.
#define OKW 16
__global__ __launch_bounds__(1024, 4)
void out_kernel(const float* __restrict__ values,
                const uint16_t* __restrict__ ctxB_hi,
                const uint16_t* __restrict__ ctxB_lo,
                float* __restrict__ out) {
    __shared__ float red[OKW][16][64];   // 64 KB
    int tid = threadIdx.x;
    int w = tid >> 6, l = tid & 63;
    int m0 = blockIdx.x * 16;
    f32x4 acc[4];
#pragma unroll
    for (int nt = 0; nt < 4; ++nt) acc[nt] = (f32x4){0.f, 0.f, 0.f, 0.f};
    int row = m0 + (l & 15);
    int kchunk = (l >> 4) * 8;
#pragma unroll
    for (int s = 0; s < 2; ++s) {
        int ks = w * 2 + s;
        int k0 = ks * 32 + kchunk;
        const float4 va0 = *reinterpret_cast<const float4*>(values + (size_t)row * F + k0);
        const float4 va1 = *reinterpret_cast<const float4*>(values + (size_t)row * F + k0 + 4);
        float av0 = va0.x, av1 = va0.y, av2 = va0.z, av3 = va0.w;
        float av4 = va1.x, av5 = va1.y, av6 = va1.z, av7 = va1.w;
        bf16x8 ahi, alo;
        {
            uint16_t h;
            h = f2bf_rne(av0); ahi[0] = (short)h; alo[0] = (short)f2bf_rne(av0 - bf2f(h));
            h = f2bf_rne(av1); ahi[1] = (short)h; alo[1] = (short)f2bf_rne(av1 - bf2f(h));
            h = f2bf_rne(av2); ahi[2] = (short)h; alo[2] = (short)f2bf_rne(av2 - bf2f(h));
            h = f2bf_rne(av3); ahi[3] = (short)h; alo[3] = (short)f2bf_rne(av3 - bf2f(h));
            h = f2bf_rne(av4); ahi[4] = (short)h; alo[4] = (short)f2bf_rne(av4 - bf2f(h));
            h = f2bf_rne(av5); ahi[5] = (short)h; alo[5] = (short)f2bf_rne(av5 - bf2f(h));
            h = f2bf_rne(av6); ahi[6] = (short)h; alo[6] = (short)f2bf_rne(av6 - bf2f(h));
            h = f2bf_rne(av7); ahi[7] = (short)h; alo[7] = (short)f2bf_rne(av7 - bf2f(h));
        }
#pragma unroll
        for (int nt = 0; nt < 4; ++nt) {
            int boff = ((ks * 4 + nt) * 64 + l) * 8;
            bf16x8 bhi = *reinterpret_cast<const bf16x8*>(ctxB_hi + boff);
            bf16x8 blo = *reinterpret_cast<const bf16x8*>(ctxB_lo + boff);
            acc[nt] = __builtin_amdgcn_mfma_f32_16x16x32_bf16(ahi, bhi, acc[nt], 0, 0, 0);
            acc[nt] = __builtin_amdgcn_mfma_f32_16x16x32_bf16(ahi, blo, acc[nt], 0, 0, 0);
            acc[nt] = __builtin_amdgcn_mfma_f32_16x16x32_bf16(alo, bhi, acc[nt], 0, 0, 0);
        }
    }
    // C/D layout: col = l&15, row = (l>>4)*4 + r   [verified m89]
#pragma unroll
    for (int nt = 0; nt < 4; ++nt)
#pragma unroll
        for (int r = 0; r < 4; ++r) {
            int orow = (l >> 4) * 4 + r;
            int ocol = nt * 16 + (l & 15);
            red[w][orow][ocol] = acc[nt][r];
        }
    __syncthreads();
    int orow = tid >> 6, ocol = tid & 63;
    float s2 = 0.f;
#pragma unroll
    for (int ww = 0; ww < OKW; ++ww) s2 += red[ww][orow][ocol];
    out[(size_t)(m0 + orow) * D + ocol] = s2;
}

extern "C" void kernel_launch(void* const* d_in, const int* in_sizes, int n_in,
                              void* d_out, int out_size, void* d_ws, size_t ws_size,
                              hipStream_t stream) {
    const float* values     = (const float*)d_in[0];
    const float* feat_emb   = (const float*)d_in[1];
    const float* hidden_emb = (const float*)d_in[2];
    const float* w_kernel   = (const float*)d_in[3];
    const float* w_bias     = (const float*)d_in[4];
    const float* u_kernel   = (const float*)d_in[5];
    const void*  mask       = (const void*)d_in[6];
    float* out = (float*)d_out;

    int*      flag    = (int*)d_ws;
    float*    wsf     = (float*)d_ws;
    float*    fp      = wsf + 64;              // F*D floats
    float*    gp      = fp + F * D;            // NN*D floats
    uint16_t* ctxB_hi = (uint16_t*)(gp + NN * D);   // 32*4*64*8 = 65536 ushorts
    uint16_t* ctxB_lo = ctxB_hi + 32 * 4 * 64 * 8;

    proj_kernel<<<(F + NN) / 4 + 1, 256, 0, stream>>>(feat_emb, hidden_emb, w_kernel,
                                                      mask, fp, gp, flag);
    attn_ctx_kernel<<<F, 256, 0, stream>>>(feat_emb, hidden_emb, mask, w_bias,
                                           u_kernel, fp, gp, flag, ctxB_hi, ctxB_lo);
    out_kernel<<<B / 16, 1024, 0, stream>>>(values, ctxB_hi, ctxB_lo, out);
}

// Round 7
// 25.263 us; speedup vs baseline: 3.8965x; 1.1244x over previous
//
#include <hip/hip_runtime.h>
#include <stdint.h>

#define F 1024
#define H 256
#define E 64
#define D 64
#define B 4096
#define NN 1280  // N = F + H

typedef __attribute__((ext_vector_type(8))) short bf16x8;
typedef __attribute__((ext_vector_type(4))) float f32x4;

__device__ inline uint16_t f2bf_rne(float x) {
    union { float f; uint32_t u; } v; v.f = x;
    uint32_t u = v.u + 0x7fffu + ((v.u >> 16) & 1u);
    return (uint16_t)(u >> 16);
}
__device__ inline float bf2f(uint16_t h) {
    union { uint32_t u; float f; } v; v.u = ((uint32_t)h) << 16;
    return v.f;
}

// ---------------- probe (extra block of proj kernel) ----------
__device__ void probe_mask_body(const void* __restrict__ mask, int* __restrict__ flag) {
    __shared__ int s_byte, s_int, s_float;
    int t = threadIdx.x;
    if (t == 0) { s_byte = 1; s_int = 1; s_float = 1; }
    __syncthreads();
    long idx = (long)t * NN + t;
    const uint8_t* mb = (const uint8_t*)mask;
    const int*     mi = (const int*)mask;
    const float*   mf = (const float*)mask;
    if (mb[idx] != 1)    atomicAnd(&s_byte, 0);
    if (mi[idx] != 1)    atomicAnd(&s_int, 0);
    if (mf[idx] != 1.0f) atomicAnd(&s_float, 0);
    __syncthreads();
    if (t == 0) {
        int mode = 0;
        if (s_byte) mode = 0;
        else if (s_int) mode = 1;
        else if (s_float) mode = 2;
        flag[0] = mode;
    }
}

// ---------------- K1: feat_proj (F x D), full_proj (NN x D), + probe --------
__global__ void proj_kernel(const float* __restrict__ feat_emb,
                            const float* __restrict__ hidden_emb,
                            const float* __restrict__ w_kernel,
                            const void*  __restrict__ mask,
                            float* __restrict__ fp, float* __restrict__ gp,
                            int* __restrict__ flag) {
    if (blockIdx.x == (F + NN) / 4) {  // last block: mask dtype probe
        probe_mask_body(mask, flag);
        return;
    }
    int tid = threadIdx.x;
    int r = blockIdx.x * 4 + (tid >> 6);
    int d = tid & 63;
    const float* emb;
    const float* W;
    float* outp;
    if (r < F) {
        emb = feat_emb + (size_t)r * E;
        W = w_kernel;                      // Wa
        outp = fp + (size_t)r * D + d;
    } else {
        int rn = r - F;
        emb = (rn < F) ? (feat_emb + (size_t)rn * E)
                       : (hidden_emb + (size_t)(rn - F) * E);
        W = w_kernel + (size_t)E * D;      // Wb
        outp = gp + (size_t)rn * D + d;
    }
    // 4 independent accumulators: break the 64-deep dependent fmaf chain
    float a0 = 0.f, a1 = 0.f, a2 = 0.f, a3 = 0.f;
#pragma unroll
    for (int e = 0; e < E; e += 4) {
        a0 = fmaf(emb[e + 0], W[(e + 0) * D + d], a0);
        a1 = fmaf(emb[e + 1], W[(e + 1) * D + d], a1);
        a2 = fmaf(emb[e + 2], W[(e + 2) * D + d], a2);
        a3 = fmaf(emb[e + 3], W[(e + 3) * D + d], a3);
    }
    *outp = (a0 + a1) + (a2 + a3);
}

// ---------------- K2: masked score -> softmax -> context (packed bf16 hi/lo) --
// 1 block per row f; 4 waves split the 1280 cols (5 x 64 chunks each).
// Two-phase: (a) ballot-compact nonzero indices to LDS via prefix popcount,
// (b) process in batches of 4 with all loads issued before compute (hides the
// ~500cyc L2 latency that previously serialized per entry). Fast tanh/exp.
__global__ __launch_bounds__(256)
void attn_ctx_kernel(const float* __restrict__ feat_emb,
                     const float* __restrict__ hidden_emb,
                     const void*  __restrict__ mask,
                     const float* __restrict__ w_bias,
                     const float* __restrict__ u_kernel,
                     const float* __restrict__ fp,
                     const float* __restrict__ gp,
                     const int*   __restrict__ flag,
                     uint16_t* __restrict__ ctxB_hi,
                     uint16_t* __restrict__ ctxB_lo) {
    __shared__ float s_cacc[4][64];
    __shared__ float s_den[4];
    __shared__ unsigned short s_idx[4][320];
    int tid = threadIdx.x;
    int w = tid >> 6, lane = tid & 63;
    int f = blockIdx.x;
    int mode = flag[0];
    float uk  = u_kernel[lane];
    float bv  = w_bias[lane];
    float fpv = fp[(size_t)f * D + lane];
    const uint8_t* mb = (const uint8_t*)mask;
    const int*     mi = (const int*)mask;
    const float*   mf = (const float*)mask;

    // phase a: load 5 mask chunks (independent), ballot, compact to LDS
    bool mv[5];
    long base = (long)f * NN + w * 320;
#pragma unroll
    for (int c = 0; c < 5; ++c) {
        long midx = base + c * 64 + lane;
        if (mode == 0)      mv[c] = (mb[midx] != 0);
        else if (mode == 1) mv[c] = (mi[midx] != 0);
        else                mv[c] = (mf[midx] != 0.f);
    }
    unsigned long long below = lane ? (~0ull >> (64 - lane)) : 0ull;
    int cnt = 0;
#pragma unroll
    for (int c = 0; c < 5; ++c) {
        unsigned long long bal = __ballot(mv[c]);
        if (mv[c]) {
            int pos = cnt + __popcll(bal & below);
            s_idx[w][pos] = (unsigned short)(w * 320 + c * 64 + lane);
        }
        cnt += __popcll(bal);   // wave-uniform
    }

    // phase b: batches of 4, loads first
    float denom = 0.f, cacc = 0.f;
    const float k2E = 2.885390082f;   // 2*log2(e)
    const float kE  = 1.44269504f;    // log2(e)
    for (int i = 0; i < cnt; i += 4) {
        int   n[4];
        float g[4], fv[4];
        bool  valid[4];
#pragma unroll
        for (int j = 0; j < 4; ++j) {
            valid[j] = (i + j) < cnt;
            n[j] = s_idx[w][valid[j] ? i + j : i];
        }
#pragma unroll
        for (int j = 0; j < 4; ++j) g[j] = gp[(size_t)n[j] * D + lane];
#pragma unroll
        for (int j = 0; j < 4; ++j)
            fv[j] = (n[j] < F) ? feat_emb[(size_t)n[j] * E + lane]
                               : hidden_emb[(size_t)(n[j] - F) * E + lane];
#pragma unroll
        for (int j = 0; j < 4; ++j) {
            float x  = fpv + g[j] + bv;
            float ax = fminf(fabsf(x), 10.f);
            float ex = exp2f(k2E * ax);                      // e^{2|x|}
            float th = (ex - 1.f) * __builtin_amdgcn_rcpf(ex + 1.f);
            th = copysignf(th, x);
            float t = uk * th;
#pragma unroll
            for (int off = 32; off; off >>= 1) t += __shfl_xor(t, off);
            float es = exp2f(t * kE);                        // uniform across lanes
            if (valid[j]) {
                denom += es;
                cacc = fmaf(es, fv[j], cacc);
            }
        }
    }
    s_cacc[w][lane] = cacc;
    if (lane == 0) s_den[w] = denom;
    __syncthreads();
    if (w == 0) {
        float c = s_cacc[0][lane] + s_cacc[1][lane] + s_cacc[2][lane] + s_cacc[3][lane];
        float dn = s_den[0] + s_den[1] + s_den[2] + s_den[3];
        c /= dn;
        uint16_t hi = f2bf_rne(c);
        float lof = c - bf2f(hi);
        uint16_t lo = f2bf_rne(lof);
        int ks = f >> 5, kk = f & 31;
        int ch = kk >> 3, j = kk & 7;
        int l  = ch * 16 + (lane & 15);
        int nt = lane >> 4;
        int off = ((ks * 4 + nt) * 64 + l) * 8 + j;
        ctxB_hi[off] = hi;
        ctxB_lo[off] = lo;
    }
}

// ---------------- K3: out = values @ ctx via split-bf16 MFMA -----------------
// Grid 256 blocks x 1024 thr (16 waves). Block owns 16 output rows (one MFMA
// m-tile), full N=64 (4 n-tiles). Wave w covers k in [w*64, w*64+64) = 2
// k-steps of 32. A-fragments loaded straight from fp32 values (2 float4/lane,
// 128B-chunk coalesced) and split to bf16 hi/lo in-register. B-fragments are
// pre-packed contiguous 16B/lane. hi*hi + hi*lo + lo*hi. LDS reduce 16 partials.
#define OKW 16
__global__ __launch_bounds__(1024, 4)
void out_kernel(const float* __restrict__ values,
                const uint16_t* __restrict__ ctxB_hi,
                const uint16_t* __restrict__ ctxB_lo,
                float* __restrict__ out) {
    __shared__ float red[OKW][16][64];   // 64 KB
    int tid = threadIdx.x;
    int w = tid >> 6, l = tid & 63;
    int m0 = blockIdx.x * 16;
    f32x4 acc[4];
#pragma unroll
    for (int nt = 0; nt < 4; ++nt) acc[nt] = (f32x4){0.f, 0.f, 0.f, 0.f};
    int row = m0 + (l & 15);
    int kchunk = (l >> 4) * 8;
#pragma unroll
    for (int s = 0; s < 2; ++s) {
        int ks = w * 2 + s;
        int k0 = ks * 32 + kchunk;
        const float4 va0 = *reinterpret_cast<const float4*>(values + (size_t)row * F + k0);
        const float4 va1 = *reinterpret_cast<const float4*>(values + (size_t)row * F + k0 + 4);
        float av0 = va0.x, av1 = va0.y, av2 = va0.z, av3 = va0.w;
        float av4 = va1.x, av5 = va1.y, av6 = va1.z, av7 = va1.w;
        bf16x8 ahi, alo;
        {
            uint16_t h;
            h = f2bf_rne(av0); ahi[0] = (short)h; alo[0] = (short)f2bf_rne(av0 - bf2f(h));
            h = f2bf_rne(av1); ahi[1] = (short)h; alo[1] = (short)f2bf_rne(av1 - bf2f(h));
            h = f2bf_rne(av2); ahi[2] = (short)h; alo[2] = (short)f2bf_rne(av2 - bf2f(h));
            h = f2bf_rne(av3); ahi[3] = (short)h; alo[3] = (short)f2bf_rne(av3 - bf2f(h));
            h = f2bf_rne(av4); ahi[4] = (short)h; alo[4] = (short)f2bf_rne(av4 - bf2f(h));
            h = f2bf_rne(av5); ahi[5] = (short)h; alo[5] = (short)f2bf_rne(av5 - bf2f(h));
            h = f2bf_rne(av6); ahi[6] = (short)h; alo[6] = (short)f2bf_rne(av6 - bf2f(h));
            h = f2bf_rne(av7); ahi[7] = (short)h; alo[7] = (short)f2bf_rne(av7 - bf2f(h));
        }
#pragma unroll
        for (int nt = 0; nt < 4; ++nt) {
            int boff = ((ks * 4 + nt) * 64 + l) * 8;
            bf16x8 bhi = *reinterpret_cast<const bf16x8*>(ctxB_hi + boff);
            bf16x8 blo = *reinterpret_cast<const bf16x8*>(ctxB_lo + boff);
            acc[nt] = __builtin_amdgcn_mfma_f32_16x16x32_bf16(ahi, bhi, acc[nt], 0, 0, 0);
            acc[nt] = __builtin_amdgcn_mfma_f32_16x16x32_bf16(ahi, blo, acc[nt], 0, 0, 0);
            acc[nt] = __builtin_amdgcn_mfma_f32_16x16x32_bf16(alo, bhi, acc[nt], 0, 0, 0);
        }
    }
    // C/D layout: col = l&15, row = (l>>4)*4 + r   [verified m89]
#pragma unroll
    for (int nt = 0; nt < 4; ++nt)
#pragma unroll
        for (int r = 0; r < 4; ++r) {
            int orow = (l >> 4) * 4 + r;
            int ocol = nt * 16 + (l & 15);
            red[w][orow][ocol] = acc[nt][r];
        }
    __syncthreads();
    int orow = tid >> 6, ocol = tid & 63;
    float s2 = 0.f;
#pragma unroll
    for (int ww = 0; ww < OKW; ++ww) s2 += red[ww][orow][ocol];
    out[(size_t)(m0 + orow) * D + ocol] = s2;
}

extern "C" void kernel_launch(void* const* d_in, const int* in_sizes, int n_in,
                              void* d_out, int out_size, void* d_ws, size_t ws_size,
                              hipStream_t stream) {
    const float* values     = (const float*)d_in[0];
    const float* feat_emb   = (const float*)d_in[1];
    const float* hidden_emb = (const float*)d_in[2];
    const float* w_kernel   = (const float*)d_in[3];
    const float* w_bias     = (const float*)d_in[4];
    const float* u_kernel   = (const float*)d_in[5];
    const void*  mask       = (const void*)d_in[6];
    float* out = (float*)d_out;

    int*      flag    = (int*)d_ws;
    float*    wsf     = (float*)d_ws;
    float*    fp      = wsf + 64;              // F*D floats
    float*    gp      = fp + F * D;            // NN*D floats
    uint16_t* ctxB_hi = (uint16_t*)(gp + NN * D);   // 32*4*64*8 = 65536 ushorts
    uint16_t* ctxB_lo = ctxB_hi + 32 * 4 * 64 * 8;

    proj_kernel<<<(F + NN) / 4 + 1, 256, 0, stream>>>(feat_emb, hidden_emb, w_kernel,
                                                      mask, fp, gp, flag);
    attn_ctx_kernel<<<F, 256, 0, stream>>>(feat_emb, hidden_emb, mask, w_bias,
                                           u_kernel, fp, gp, flag, ctxB_hi, ctxB_lo);
    out_kernel<<<B / 16, 1024, 0, stream>>>(values, ctxB_hi, ctxB_lo, out);
}